// Round 3
// baseline (166.154 us; speedup 1.0000x reference)
//
#include <hip/hip_runtime.h>
#include <hip/hip_bf16.h>

#define N_ITEMS 8192
#define DIM 64
#define BATCH 4096
#define NCLASS 50
#define JS 16                          // grid.y j-splits
#define WPB 4                          // waves per block
#define JR (N_ITEMS / (JS * WPB))      // 128 j-rows per wave
#define NTILES (JR / 32)               // 4 tiles of 32 j-rows
#define INV_T (1.0f / 0.07f)
#define LOG2E 1.4426950408889634f

typedef __bf16 bf16_t;
typedef __attribute__((ext_vector_type(8))) __bf16 bf16x8;
typedef __attribute__((ext_vector_type(16))) float f32x16;

#if __has_builtin(__builtin_amdgcn_exp2f)
#define EXP2(x) __builtin_amdgcn_exp2f(x)
#else
#define EXP2(x) __expf((x) * 0.6931471805599453f)
#endif

__device__ __forceinline__ float wave_sum(float v) {
    #pragma unroll
    for (int off = 32; off; off >>= 1) v += __shfl_xor(v, off, 64);
    return v;
}

// Fused prep (normalize -> featB bf16, m, S=0, hist, class sums g) + rating.
// Blocks [0,2048): prep, 4 rows each. Blocks [2048,3072): rating, 4 rows each.
__global__ __launch_bounds__(256) void prep_rating(
    const float* __restrict__ emb, const int* __restrict__ labels,
    const int* __restrict__ idx, const float* __restrict__ aw,
    const float* __restrict__ ab,
    bf16_t* __restrict__ featB, float* __restrict__ m_arr,
    float* __restrict__ S, float* __restrict__ g, int* __restrict__ hist,
    float* __restrict__ out) {
    int t = threadIdx.x, lane = t & 63, w = t >> 6;
    int bid = blockIdx.x;
    if (bid < N_ITEMS / 4) {
        int row = bid * 4 + w;
        float x = emb[row * DIM + lane];
        float ss = wave_sum(x * x);
        float f = x / fmaxf(sqrtf(ss), 1e-12f);
        featB[row * DIM + lane] = (bf16_t)f;
        float sd = wave_sum(f * f);
        int l = labels[row];
        unsafeAtomicAdd(&g[l * DIM + lane], f);
        if (lane == 0) {
            m_arr[row] = sd * INV_T;
            S[row] = 0.f;
            atomicAdd(&hist[l], 1);
        }
        if (row == 0 && lane == 1) out[BATCH] = 0.f;  // zero the loss slot
    } else {
        int row = (bid - N_ITEMS / 4) * 4 + w;
        int it = idx[row];
        float x = emb[it * DIM + lane] * aw[lane];
        x = wave_sum(x);
        if (lane == 0) out[row] = 1.0f / (1.0f + __expf(-(x + ab[0])));
    }
}

// MFMA Gram matrix, S-only fused epilogue. BI=64: two 32x32 i-tiles per wave.
// Lane owns i-col (lane&31); accS accumulated per-lane, one shfl + atomic at end.
__global__ __launch_bounds__(256) void supcon_mfma(
    const bf16_t* __restrict__ featB, const float* __restrict__ m_arr,
    float* __restrict__ S_out) {
    const float scale = INV_T * LOG2E;
    int t = threadIdx.x;
    int lane = t & 63;
    int wv = t >> 6;
    int col = lane & 31;
    int half = lane >> 5;
    int i0 = blockIdx.x * 64;
    int ig0 = i0 + col, ig1 = i0 + 32 + col;
    float bias0 = -m_arr[ig0] * LOG2E;
    float bias1 = -m_arr[ig1] * LOG2E;

    // B frags for the two i-groups (identical addressing to A — Gram matrix)
    bf16x8 bf0[4], bf1[4];
    const bf16_t* b0p = featB + (size_t)ig0 * DIM + half * 8;
    const bf16_t* b1p = featB + (size_t)ig1 * DIM + half * 8;
    #pragma unroll
    for (int s = 0; s < 4; ++s) {
        bf0[s] = *reinterpret_cast<const bf16x8*>(b0p + s * 16);
        bf1[s] = *reinterpret_cast<const bf16x8*>(b1p + s * 16);
    }

    int jbase = (blockIdx.y * WPB + wv) * JR;
    int rowoff = half * 4;
    float p0[4] = {0.f, 0.f, 0.f, 0.f}, p1[4] = {0.f, 0.f, 0.f, 0.f};

    for (int tile = 0; tile < NTILES; ++tile) {
        int jt = jbase + tile * 32;
        const bf16_t* arowp = featB + (size_t)(jt + col) * DIM + half * 8;
        f32x16 c0 = {}, c1 = {};
        #pragma unroll
        for (int s = 0; s < 4; ++s) {
            bf16x8 a = *reinterpret_cast<const bf16x8*>(arowp + s * 16);
            c0 = __builtin_amdgcn_mfma_f32_32x32x16_bf16(a, bf0[s], c0, 0, 0, 0);
            c1 = __builtin_amdgcn_mfma_f32_32x32x16_bf16(a, bf1[s], c1, 0, 0, 0);
        }
        if (jt != i0) {
            #pragma unroll
            for (int r = 0; r < 16; ++r)
                p0[r & 3] += EXP2(fmaf(c0[r], scale, bias0));
        } else {
            #pragma unroll
            for (int r = 0; r < 16; ++r) {
                int jrow = (r & 3) + 8 * (r >> 2) + rowoff;
                float e = EXP2(fmaf(c0[r], scale, bias0));
                p0[r & 3] += (jrow != col) ? e : 0.f;
            }
        }
        if (jt != i0 + 32) {
            #pragma unroll
            for (int r = 0; r < 16; ++r)
                p1[r & 3] += EXP2(fmaf(c1[r], scale, bias1));
        } else {
            #pragma unroll
            for (int r = 0; r < 16; ++r) {
                int jrow = (r & 3) + 8 * (r >> 2) + rowoff;
                float e = EXP2(fmaf(c1[r], scale, bias1));
                p1[r & 3] += (jrow != col) ? e : 0.f;
            }
        }
    }
    float a0 = (p0[0] + p0[1]) + (p0[2] + p0[3]);
    float a1 = (p1[0] + p1[1]) + (p1[2] + p1[3]);
    a0 += __shfl_xor(a0, 32, 64);
    a1 += __shfl_xor(a1, 32, 64);
    if (lane < 32) {
        unsafeAtomicAdd(&S_out[ig0], a0);
        unsafeAtomicAdd(&S_out[ig1], a1);
    }
}

// Parallel finalize: wave per row (grid-stride), P_i = feat_i . g[l_i] / T - m_i,
// val = (P - C*(m + log(S+1e-6))) / (C+1e-6); block-reduce, atomic into loss.
__global__ __launch_bounds__(256) void finalize_kernel(
    const bf16_t* __restrict__ featB, const float* __restrict__ g,
    const float* __restrict__ S, const float* __restrict__ m_arr,
    const int* __restrict__ labels, const int* __restrict__ hist,
    float* __restrict__ out_loss) {
    __shared__ float red[4];
    int t = threadIdx.x, lane = t & 63, w = t >> 6;
    int wid = blockIdx.x * 4 + w;          // 0..127
    float acc = 0.f;
    for (int r = wid; r < N_ITEMS; r += 128) {
        int l = labels[r];
        float f = (float)featB[r * DIM + lane];
        float gv = g[l * DIM + lane];
        float dot = wave_sum(f * gv);
        float m = m_arr[r];
        float C = (float)(hist[l] - 1);
        float P = dot * INV_T - m;
        acc += (P - C * (m + __logf(S[r] + 1e-6f))) / (C + 1e-6f);
    }
    if (lane == 0) red[w] = acc;
    __syncthreads();
    if (t == 0) {
        float v = (red[0] + red[1]) + (red[2] + red[3]);
        unsafeAtomicAdd(out_loss, -v / (float)N_ITEMS);
    }
}

extern "C" void kernel_launch(void* const* d_in, const int* in_sizes, int n_in,
                              void* d_out, int out_size, void* d_ws, size_t ws_size,
                              hipStream_t stream) {
    const int*   item_indices = (const int*)d_in[0];
    const int*   labels       = (const int*)d_in[1];
    const float* emb          = (const float*)d_in[2];
    const float* aw           = (const float*)d_in[3];
    const float* ab           = (const float*)d_in[4];
    float* out = (float*)d_out;   // [4096 ratings][1 supcon]

    bf16_t* featB = (bf16_t*)d_ws;                       // 8192*64 bf16 (1 MB)
    float*  m_arr = (float*)(featB + N_ITEMS * DIM);     // 8192
    float*  S     = m_arr + N_ITEMS;                     // 8192
    float*  g     = S + N_ITEMS;                         // 50*64 class sums
    int*    hist  = (int*)(g + NCLASS * DIM);            // 64 (50 used)

    // zero g + hist (contiguous); S and loss slot zeroed inside prep_rating
    hipMemsetAsync(g, 0, (size_t)(NCLASS * DIM + 64) * sizeof(float), stream);

    prep_rating<<<N_ITEMS / 4 + BATCH / 4, 256, 0, stream>>>(
        emb, labels, item_indices, aw, ab, featB, m_arr, S, g, hist, out);

    dim3 grid(N_ITEMS / 64, JS);
    supcon_mfma<<<grid, 256, 0, stream>>>(featB, m_arr, S);

    finalize_kernel<<<32, 256, 0, stream>>>(featB, g, S, m_arr, labels, hist,
                                            out + BATCH);
}

// Round 4
// 153.714 us; speedup vs baseline: 1.0809x; 1.0809x over previous
//
#include <hip/hip_runtime.h>
#include <hip/hip_bf16.h>

#define N_ITEMS 8192
#define DIM 64
#define BATCH 4096
#define NCLASS 50
#define JS 16                          // grid.y j-splits
#define WPB 4                          // waves per block
#define JR (N_ITEMS / (JS * WPB))      // 128 j-rows per wave
#define NTILES (JR / 32)               // 4 tiles of 32 j-rows
#define INV_T (1.0f / 0.07f)
#define LOG2E 1.4426950408889634f

typedef __bf16 bf16_t;
typedef __attribute__((ext_vector_type(8))) __bf16 bf16x8;
typedef __attribute__((ext_vector_type(16))) float f32x16;

#if __has_builtin(__builtin_amdgcn_exp2f)
#define EXP2(x) __builtin_amdgcn_exp2f(x)
#else
#define EXP2(x) __expf((x) * 0.6931471805599453f)
#endif

__device__ __forceinline__ float wave_sum(float v) {
    #pragma unroll
    for (int off = 32; off; off >>= 1) v += __shfl_xor(v, off, 64);
    return v;
}

// Fused prep (normalize -> featB bf16, m, S=0, hist, class sums g) + rating.
// Blocks [0,2048): prep, 4 rows each. Blocks [2048,3072): rating, 4 rows each.
__global__ __launch_bounds__(256) void prep_rating(
    const float* __restrict__ emb, const int* __restrict__ labels,
    const int* __restrict__ idx, const float* __restrict__ aw,
    const float* __restrict__ ab,
    bf16_t* __restrict__ featB, float* __restrict__ m_arr,
    float* __restrict__ S, float* __restrict__ g, int* __restrict__ hist,
    float* __restrict__ out) {
    int t = threadIdx.x, lane = t & 63, w = t >> 6;
    int bid = blockIdx.x;
    if (bid < N_ITEMS / 4) {
        int row = bid * 4 + w;
        float x = emb[row * DIM + lane];
        float ss = wave_sum(x * x);
        float f = x / fmaxf(sqrtf(ss), 1e-12f);
        featB[row * DIM + lane] = (bf16_t)f;
        float sd = wave_sum(f * f);
        int l = labels[row];
        unsafeAtomicAdd(&g[l * DIM + lane], f);
        if (lane == 0) {
            m_arr[row] = sd * INV_T;
            S[row] = 0.f;
            atomicAdd(&hist[l], 1);
        }
    } else {
        int row = (bid - N_ITEMS / 4) * 4 + w;
        int it = idx[row];
        float x = emb[it * DIM + lane] * aw[lane];
        x = wave_sum(x);
        if (lane == 0) out[row] = 1.0f / (1.0f + __expf(-(x + ab[0])));
    }
}

// MFMA Gram matrix, S-only fused epilogue. BI=64: two 32x32 i-tiles per wave.
// Lane owns i-col (lane&31); accS accumulated per-lane, one shfl + atomic at end.
__global__ __launch_bounds__(256) void supcon_mfma(
    const bf16_t* __restrict__ featB, const float* __restrict__ m_arr,
    float* __restrict__ S_out) {
    const float scale = INV_T * LOG2E;
    int t = threadIdx.x;
    int lane = t & 63;
    int wv = t >> 6;
    int col = lane & 31;
    int half = lane >> 5;
    int i0 = blockIdx.x * 64;
    int ig0 = i0 + col, ig1 = i0 + 32 + col;
    float bias0 = -m_arr[ig0] * LOG2E;
    float bias1 = -m_arr[ig1] * LOG2E;

    // B frags for the two i-groups (identical addressing to A — Gram matrix)
    bf16x8 bf0[4], bf1[4];
    const bf16_t* b0p = featB + (size_t)ig0 * DIM + half * 8;
    const bf16_t* b1p = featB + (size_t)ig1 * DIM + half * 8;
    #pragma unroll
    for (int s = 0; s < 4; ++s) {
        bf0[s] = *reinterpret_cast<const bf16x8*>(b0p + s * 16);
        bf1[s] = *reinterpret_cast<const bf16x8*>(b1p + s * 16);
    }

    int jbase = (blockIdx.y * WPB + wv) * JR;
    int rowoff = half * 4;
    float p0[4] = {0.f, 0.f, 0.f, 0.f}, p1[4] = {0.f, 0.f, 0.f, 0.f};

    for (int tile = 0; tile < NTILES; ++tile) {
        int jt = jbase + tile * 32;
        const bf16_t* arowp = featB + (size_t)(jt + col) * DIM + half * 8;
        f32x16 c0 = {}, c1 = {};
        #pragma unroll
        for (int s = 0; s < 4; ++s) {
            bf16x8 a = *reinterpret_cast<const bf16x8*>(arowp + s * 16);
            c0 = __builtin_amdgcn_mfma_f32_32x32x16_bf16(a, bf0[s], c0, 0, 0, 0);
            c1 = __builtin_amdgcn_mfma_f32_32x32x16_bf16(a, bf1[s], c1, 0, 0, 0);
        }
        if (jt != i0) {
            #pragma unroll
            for (int r = 0; r < 16; ++r)
                p0[r & 3] += EXP2(fmaf(c0[r], scale, bias0));
        } else {
            #pragma unroll
            for (int r = 0; r < 16; ++r) {
                int jrow = (r & 3) + 8 * (r >> 2) + rowoff;
                float e = EXP2(fmaf(c0[r], scale, bias0));
                p0[r & 3] += (jrow != col) ? e : 0.f;
            }
        }
        if (jt != i0 + 32) {
            #pragma unroll
            for (int r = 0; r < 16; ++r)
                p1[r & 3] += EXP2(fmaf(c1[r], scale, bias1));
        } else {
            #pragma unroll
            for (int r = 0; r < 16; ++r) {
                int jrow = (r & 3) + 8 * (r >> 2) + rowoff;
                float e = EXP2(fmaf(c1[r], scale, bias1));
                p1[r & 3] += (jrow != col) ? e : 0.f;
            }
        }
    }
    float a0 = (p0[0] + p0[1]) + (p0[2] + p0[3]);
    float a1 = (p1[0] + p1[1]) + (p1[2] + p1[3]);
    a0 += __shfl_xor(a0, 32, 64);
    a1 += __shfl_xor(a1, 32, 64);
    if (lane < 32) {
        unsafeAtomicAdd(&S_out[ig0], a0);
        unsafeAtomicAdd(&S_out[ig1], a1);
    }
}

// Single-block finalize via per-class decomposition:
//   sum_{i in c} feat_i . g_c = |g_c|^2
//   term_c = (|g_c|^2/T - (1+C_c)*Msum_c - C_c*Lsum_c) / (C_c + 1e-6), 0 if C_c<1
//   loss = -(sum_c term_c) / N
// Phase 1: bin m_i and log(S_i+1e-6) into LDS class bins (8 rows/thread).
// Phase 2: one wave per class computes |g_c|^2 and the class term.
__global__ __launch_bounds__(1024) void finalize_all(
    const float* __restrict__ S, const float* __restrict__ m_arr,
    const int* __restrict__ labels, const int* __restrict__ hist,
    const float* __restrict__ g, float* __restrict__ out_loss) {
    __shared__ float msum[NCLASS], lsum[NCLASS];
    __shared__ float red[16];
    int t = threadIdx.x;
    if (t < NCLASS) { msum[t] = 0.f; lsum[t] = 0.f; }
    __syncthreads();
    #pragma unroll
    for (int e = 0; e < N_ITEMS / 1024; ++e) {
        int r = t + e * 1024;
        int l = labels[r];
        atomicAdd(&msum[l], m_arr[r]);
        atomicAdd(&lsum[l], __logf(S[r] + 1e-6f));
    }
    __syncthreads();
    int lane = t & 63, w = t >> 6;   // 16 waves
    float acc = 0.f;
    for (int c = w; c < NCLASS; c += 16) {
        float gv = g[c * DIM + lane];
        float dot = wave_sum(gv * gv);
        float C = (float)(hist[c] - 1);
        float term = (C > 0.5f)
            ? (dot * INV_T - (1.f + C) * msum[c] - C * lsum[c]) / (C + 1e-6f)
            : 0.f;
        if (lane == 0) acc += term;
    }
    if (lane == 0) red[w] = acc;
    __syncthreads();
    if (t == 0) {
        float v = 0.f;
        #pragma unroll
        for (int i = 0; i < 16; ++i) v += red[i];
        out_loss[0] = -v / (float)N_ITEMS;
    }
}

extern "C" void kernel_launch(void* const* d_in, const int* in_sizes, int n_in,
                              void* d_out, int out_size, void* d_ws, size_t ws_size,
                              hipStream_t stream) {
    const int*   item_indices = (const int*)d_in[0];
    const int*   labels       = (const int*)d_in[1];
    const float* emb          = (const float*)d_in[2];
    const float* aw           = (const float*)d_in[3];
    const float* ab           = (const float*)d_in[4];
    float* out = (float*)d_out;   // [4096 ratings][1 supcon]

    bf16_t* featB = (bf16_t*)d_ws;                       // 8192*64 bf16 (1 MB)
    float*  m_arr = (float*)(featB + N_ITEMS * DIM);     // 8192
    float*  S     = m_arr + N_ITEMS;                     // 8192
    float*  g     = S + N_ITEMS;                         // 50*64 class sums
    int*    hist  = (int*)(g + NCLASS * DIM);            // 64 (50 used)

    // zero g + hist (contiguous); S zeroed inside prep_rating
    hipMemsetAsync(g, 0, (size_t)(NCLASS * DIM + 64) * sizeof(float), stream);

    prep_rating<<<N_ITEMS / 4 + BATCH / 4, 256, 0, stream>>>(
        emb, labels, item_indices, aw, ab, featB, m_arr, S, g, hist, out);

    dim3 grid(N_ITEMS / 64, JS);
    supcon_mfma<<<grid, 256, 0, stream>>>(featB, m_arr, S);

    finalize_all<<<1, 1024, 0, stream>>>(S, m_arr, labels, hist, g, out + BATCH);
}

// Round 5
// 112.750 us; speedup vs baseline: 1.4736x; 1.3633x over previous
//
#include <hip/hip_runtime.h>
#include <hip/hip_bf16.h>

#define N_ITEMS 8192
#define DIM 64
#define BATCH 4096
#define NCLASS 50
#define JS 16                          // grid.y j-splits
#define WPB 4                          // waves per block
#define JR (N_ITEMS / (JS * WPB))      // 128 j-rows per wave
#define NTILES (JR / 32)               // 4 tiles of 32 j-rows
#define INV_T (1.0f / 0.07f)
#define LOG2E 1.4426950408889634f

typedef __bf16 bf16_t;
typedef __attribute__((ext_vector_type(8))) __bf16 bf16x8;
typedef __attribute__((ext_vector_type(16))) float f32x16;

#if __has_builtin(__builtin_amdgcn_exp2f)
#define EXP2(x) __builtin_amdgcn_exp2f(x)
#else
#define EXP2(x) __expf((x) * 0.6931471805599453f)
#endif

__device__ __forceinline__ float wave_sum(float v) {
    #pragma unroll
    for (int off = 32; off; off >>= 1) v += __shfl_xor(v, off, 64);
    return v;
}

// Prep: normalize rows -> bf16 featB, zero S; plus rating head. NO atomics.
// Blocks [0,2048): normalize, 4 rows each. Blocks [2048,3072): rating.
__global__ __launch_bounds__(256) void prep_rating(
    const float* __restrict__ emb, const int* __restrict__ idx,
    const float* __restrict__ aw, const float* __restrict__ ab,
    bf16_t* __restrict__ featB, float* __restrict__ S,
    float* __restrict__ out) {
    int t = threadIdx.x, lane = t & 63, w = t >> 6;
    int bid = blockIdx.x;
    if (bid < N_ITEMS / 4) {
        int row = bid * 4 + w;
        float x = emb[row * DIM + lane];
        float ss = wave_sum(x * x);
        float f = x * __frsqrt_rn(fmaxf(ss, 1e-24f));
        featB[row * DIM + lane] = (bf16_t)f;
        if (lane == 0) S[row] = 0.f;
        if (bid == 0 && t == 0) out[BATCH] = 0.f;   // zero the loss slot
    } else {
        int row = (bid - N_ITEMS / 4) * 4 + w;
        int it = idx[row];
        float x = emb[it * DIM + lane] * aw[lane];
        x = wave_sum(x);
        if (lane == 0) out[row] = 1.0f / (1.0f + __expf(-(x + ab[0])));
    }
}

// MFMA Gram matrix, S-only fused epilogue. BI=64: two 32x32 i-tiles per wave.
// m_i == 1/T analytically (self-cosine), so bias is a compile-time constant.
__global__ __launch_bounds__(256) void supcon_mfma(
    const bf16_t* __restrict__ featB, float* __restrict__ S_out) {
    const float scale = INV_T * LOG2E;
    const float bias = -INV_T * LOG2E;
    int t = threadIdx.x;
    int lane = t & 63;
    int wv = t >> 6;
    int col = lane & 31;
    int half = lane >> 5;
    int i0 = blockIdx.x * 64;
    int ig0 = i0 + col, ig1 = i0 + 32 + col;

    // B frags for the two i-groups (identical addressing to A — Gram matrix)
    bf16x8 bf0[4], bf1[4];
    const bf16_t* b0p = featB + (size_t)ig0 * DIM + half * 8;
    const bf16_t* b1p = featB + (size_t)ig1 * DIM + half * 8;
    #pragma unroll
    for (int s = 0; s < 4; ++s) {
        bf0[s] = *reinterpret_cast<const bf16x8*>(b0p + s * 16);
        bf1[s] = *reinterpret_cast<const bf16x8*>(b1p + s * 16);
    }

    int jbase = (blockIdx.y * WPB + wv) * JR;
    int rowoff = half * 4;
    float p0[4] = {0.f, 0.f, 0.f, 0.f}, p1[4] = {0.f, 0.f, 0.f, 0.f};

    for (int tile = 0; tile < NTILES; ++tile) {
        int jt = jbase + tile * 32;
        const bf16_t* arowp = featB + (size_t)(jt + col) * DIM + half * 8;
        f32x16 c0 = {}, c1 = {};
        #pragma unroll
        for (int s = 0; s < 4; ++s) {
            bf16x8 a = *reinterpret_cast<const bf16x8*>(arowp + s * 16);
            c0 = __builtin_amdgcn_mfma_f32_32x32x16_bf16(a, bf0[s], c0, 0, 0, 0);
            c1 = __builtin_amdgcn_mfma_f32_32x32x16_bf16(a, bf1[s], c1, 0, 0, 0);
        }
        if (jt != i0) {
            #pragma unroll
            for (int r = 0; r < 16; ++r)
                p0[r & 3] += EXP2(fmaf(c0[r], scale, bias));
        } else {
            #pragma unroll
            for (int r = 0; r < 16; ++r) {
                int jrow = (r & 3) + 8 * (r >> 2) + rowoff;
                float e = EXP2(fmaf(c0[r], scale, bias));
                p0[r & 3] += (jrow != col) ? e : 0.f;
            }
        }
        if (jt != i0 + 32) {
            #pragma unroll
            for (int r = 0; r < 16; ++r)
                p1[r & 3] += EXP2(fmaf(c1[r], scale, bias));
        } else {
            #pragma unroll
            for (int r = 0; r < 16; ++r) {
                int jrow = (r & 3) + 8 * (r >> 2) + rowoff;
                float e = EXP2(fmaf(c1[r], scale, bias));
                p1[r & 3] += (jrow != col) ? e : 0.f;
            }
        }
    }
    float a0 = (p0[0] + p0[1]) + (p0[2] + p0[3]);
    float a1 = (p1[0] + p1[1]) + (p1[2] + p1[3]);
    a0 += __shfl_xor(a0, 32, 64);
    a1 += __shfl_xor(a1, 32, 64);
    if (lane < 32) {
        unsafeAtomicAdd(&S_out[ig0], a0);
        unsafeAtomicAdd(&S_out[ig1], a1);
    }
}

// One block per class c:
//   scan labels in 64-row strips; ballot-gather matching feat rows into g_c
//   (lane = dim), count members, sum log(S+1e-6) on matching lanes.
//   term_c = (|g_c|^2/T - (1+C)*cnt/T - C*lsum) / (C+1e-6), 0 if C < 1
//   loss -= term_c / N   (only 50 atomic adds total)
__global__ __launch_bounds__(256) void finalize_class(
    const bf16_t* __restrict__ featB, const float* __restrict__ S,
    const int* __restrict__ labels, float* __restrict__ out_loss) {
    __shared__ float sg[4][DIM];
    __shared__ float sl[4], sc[4];
    int c = blockIdx.x;
    int t = threadIdx.x, lane = t & 63, w = t >> 6;
    float gacc = 0.f, lacc = 0.f, cacc = 0.f;
    for (int strip = w; strip < N_ITEMS / 64; strip += 4) {
        int r = strip * 64 + lane;
        bool match = (labels[r] == c);
        unsigned long long mask = __ballot(match);
        if (match) {
            lacc += __logf(S[r] + 1e-6f);
            cacc += 1.f;
        }
        const bf16_t* base = featB + (size_t)strip * 64 * DIM + lane;
        while (mask) {
            int b = __builtin_ctzll(mask);
            mask &= mask - 1;
            gacc += (float)base[b * DIM];
        }
    }
    lacc = wave_sum(lacc);
    cacc = wave_sum(cacc);
    sg[w][lane] = gacc;
    if (lane == 0) { sl[w] = lacc; sc[w] = cacc; }
    __syncthreads();
    if (w == 0) {
        float g = (sg[0][lane] + sg[1][lane]) + (sg[2][lane] + sg[3][lane]);
        float dot = wave_sum(g * g);
        if (lane == 0) {
            float cnt = (sc[0] + sc[1]) + (sc[2] + sc[3]);
            float ls  = (sl[0] + sl[1]) + (sl[2] + sl[3]);
            float C = cnt - 1.f;
            float term = (C > 0.5f)
                ? (dot * INV_T - (1.f + C) * cnt * INV_T - C * ls) / (C + 1e-6f)
                : 0.f;
            unsafeAtomicAdd(out_loss, -term / (float)N_ITEMS);
        }
    }
}

extern "C" void kernel_launch(void* const* d_in, const int* in_sizes, int n_in,
                              void* d_out, int out_size, void* d_ws, size_t ws_size,
                              hipStream_t stream) {
    const int*   item_indices = (const int*)d_in[0];
    const int*   labels       = (const int*)d_in[1];
    const float* emb          = (const float*)d_in[2];
    const float* aw           = (const float*)d_in[3];
    const float* ab           = (const float*)d_in[4];
    float* out = (float*)d_out;   // [4096 ratings][1 supcon]

    bf16_t* featB = (bf16_t*)d_ws;                       // 8192*64 bf16 (1 MB)
    float*  S     = (float*)(featB + N_ITEMS * DIM);     // 8192

    prep_rating<<<N_ITEMS / 4 + BATCH / 4, 256, 0, stream>>>(
        emb, item_indices, aw, ab, featB, S, out);

    dim3 grid(N_ITEMS / 64, JS);
    supcon_mfma<<<grid, 256, 0, stream>>>(featB, S);

    finalize_class<<<NCLASS, 256, 0, stream>>>(featB, S, labels, out + BATCH);
}